// Round 10
// baseline (2772.049 us; speedup 1.0000x reference)
//
#include <hip/hip_runtime.h>

// GRU: T=1024, B=256, I=H=O=256, fp32 in/out, bf16 MFMA internally.
// d_out layout: outs [T*B][O] fp32 then h_final [B][H] fp32.
// R1: LDS-only barriers. R2: VALU diet. R4: whr+whh AGPR-resident (PINned),
// whz L2-streamed via dbuf. R6/R7: log2e folding (builtins, no setprio).
// R8: xproj B-reuse (M=32/wave). 2622us = scan 2040 + others 580.
// R9: producer/consumer fusion. Grid = 16 scan blocks + 112 consumers
//     (128 <= capacity -> co-resident, no deadlock). Scan publishes progress
//     every 16 steps (threadfence + agent-scope atomic); consumers spin on
//     relaxed agent atomics then compute out-tiles (old gru_out, 512-thr).
//     xr/xz INTERLEAVED per t (combined 256KB block t == out[t] bytes) so
//     out[t] is safe once scan step t done -> gate = progress >= t+1.
//     cand (xh_p in d_ws) read by consumers after publication; producer
//     wbl2 makes it L3-fresh; consumer lines are first-touch (no inv needed).

typedef unsigned short u16t;
typedef unsigned int   u32t;
typedef short  s16x8 __attribute__((ext_vector_type(8)));
typedef float  f32x4 __attribute__((ext_vector_type(4)));
typedef float  f32v4 __attribute__((ext_vector_type(4)));
typedef u32t   u32x2 __attribute__((ext_vector_type(2)));

#define L2E 1.4426950408889634f
#define NCONS 112

// LDS-only barrier: order ds ops, leave vmcnt in flight.
#define BAR_LDS() asm volatile("s_waitcnt lgkmcnt(0)\n\ts_barrier" ::: "memory")
// Pin a value in VGPRs/AGPRs: opaque to the optimizer, no remat.
#define PIN(v) asm volatile("" : "+v"(v))

__device__ __forceinline__ float lo_f(u32t u) {
  return __builtin_bit_cast(float, u << 16);
}
__device__ __forceinline__ float hi_f(u32t u) {
  return __builtin_bit_cast(float, u & 0xffff0000u);
}
__device__ __forceinline__ u32t f2bf(float f) {  // round-to-nearest-even
  u32t u = __builtin_bit_cast(u32t, f);
  return (u + 0x7fffu + ((u >> 16) & 1u)) >> 16;
}
__device__ __forceinline__ u32t cvtpk(float lo, float hi) {  // 2xbf16 RNE pack
  u32t r;
  asm("v_cvt_pk_bf16_f32 %0, %1, %2" : "=v"(r) : "v"(lo), "v"(hi));
  return r;
}
__device__ __forceinline__ f32x4 MF(s16x8 a, s16x8 b, f32x4 c) {
  return __builtin_amdgcn_mfma_f32_16x16x32_bf16(a, b, c, 0, 0, 0);
}
// y = x*log2e folded: sigma(x) = 1/(1+2^-y)
__device__ __forceinline__ float sigm2(float y) {
  return __builtin_amdgcn_rcpf(1.0f + __builtin_amdgcn_exp2f(-y));
}
// y = x*2*log2e folded: tanh(x) = 1 - 2/(2^y + 1)
__device__ __forceinline__ float tanh2(float y) {
  return fmaf(-2.0f, __builtin_amdgcn_rcpf(__builtin_amdgcn_exp2f(y) + 1.0f), 1.0f);
}

// ---------------------------------------------------------------------------
// Pack 7 weight matrices -> bf16 MFMA-B fragments, pre-scaled (log2e folds).
// Also zeroes the 16-slot progress array (block 0).
// ---------------------------------------------------------------------------
__global__ void pack_w(const float* __restrict__ wxr, const float* __restrict__ wxz,
                       const float* __restrict__ wxh, const float* __restrict__ whr,
                       const float* __restrict__ whz, const float* __restrict__ whh,
                       const float* __restrict__ wout, u16t* __restrict__ dst,
                       int* __restrict__ prog) {
  if (blockIdx.x == 0 && threadIdx.x < 16) prog[threadIdx.x] = 0;
  int e = blockIdx.x * 256 + threadIdx.x;     // [0, 7*65536)
  int mat = e >> 16, i = e & 65535;
  const float* src = mat == 0 ? wxr : mat == 1 ? wxz : mat == 2 ? wxh
                   : mat == 3 ? whr : mat == 4 ? whz : mat == 5 ? whh : wout;
  float sc = (mat == 2 || mat == 5) ? 2.0f * L2E : (mat == 6 ? 1.0f : L2E);
  int j = i & 7, lane = (i >> 3) & 63, ks = (i >> 9) & 7, nb = i >> 12;
  int k = ks * 32 + (lane >> 4) * 8 + j;
  int n = nb * 16 + (lane & 15);
  dst[e] = (u16t)f2bf(src[k * 256 + n] * sc);
}

// ---------------------------------------------------------------------------
// Phase 1: xg = x @ Wxg + bg (pre-scaled), bf16 C-frag-packed.
// xr/xz interleaved per t: u32x2 idx = t*32768 + wg*1024 + nb*64 + lane
// (xr at block base, xz at base+16384). xh keeps stride 16384 (in d_ws).
// ---------------------------------------------------------------------------
__global__ __launch_bounds__(512, 2) void gru_xproj(
    const float* __restrict__ x, const u16t* __restrict__ wpack,
    const float* __restrict__ br, const float* __restrict__ bz,
    const float* __restrict__ bh,
    u16t* __restrict__ xr_p, u16t* __restrict__ xz_p, u16t* __restrict__ xh_p) {
  __shared__ __align__(128) u16t xt[16384];   // [64][256] bf16, XOR-swizzled
  const int tid = threadIdx.x, bid = blockIdx.x;
  const int t = bid >> 2, b0 = (bid & 3) * 64;
  const float* xrow = x + ((size_t)t * 256 + b0) * 256;
#pragma unroll
  for (int c = 0; c < 8; ++c) {
    int f4 = c * 512 + tid;                   // [0,4096) float4s
    f32v4 v = ((const f32v4*)xrow)[f4];
    u32t lo = f2bf(v[0]) | (f2bf(v[1]) << 16);
    u32t hi = f2bf(v[2]) | (f2bf(v[3]) << 16);
    int row = f4 >> 6, c8 = (f4 & 63) * 8;
    int off = (row * 512 + c8) ^ ((row & 7) << 4);
    u32x2 vv; vv[0] = lo; vv[1] = hi;
    *(u32x2*)((char*)xt + off) = vv;
  }
  __syncthreads();
  const int lane = tid & 63, w = tid >> 6;
  const int m2 = w & 1, cg = w >> 1;          // rows m2*32+..; combos cg*12+..
  const int arow = m2 * 32 + (lane & 15);     // s=0 row; s=1 -> +16
  const int abase = arow * 512 + (lane >> 4) * 16;
  const int asw = (lane & 7) << 4;
  const f32x4 Z = {0.f, 0.f, 0.f, 0.f};
  f32x4 acc[2][12];
#pragma unroll
  for (int s = 0; s < 2; ++s)
#pragma unroll
    for (int p = 0; p < 12; ++p) acc[s][p] = Z;
#pragma unroll
  for (int ks = 0; ks < 8; ++ks) {
    s16x8 a0 = *(const s16x8*)((char*)xt + ((abase + ks * 64) ^ asw));
    s16x8 a1 = *(const s16x8*)((char*)xt + ((abase + 16 * 512 + ks * 64) ^ asw));
#pragma unroll
    for (int p = 0; p < 12; ++p) {
      int pj = cg * 12 + p;
      int gate = pj >> 4, nb = pj & 15;
      const s16x8* wb = (const s16x8*)wpack + gate * 8192;
      s16x8 b = wb[(nb * 8 + ks) * 64 + lane];
      acc[0][p] = MF(a0, b, acc[0][p]);
      acc[1][p] = MF(a1, b, acc[1][p]);
    }
  }
#pragma unroll
  for (int p = 0; p < 12; ++p) {
    int pj = cg * 12 + p;
    int gate = pj >> 4, nb = pj & 15;
    const float* bp = gate == 0 ? br : gate == 1 ? bz : bh;
    float bs = (gate == 2) ? 2.0f * L2E : L2E;
    float bv = bp[nb * 16 + (lane & 15)] * bs;
    u16t* op = gate == 0 ? xr_p : gate == 1 ? xz_p : xh_p;
#pragma unroll
    for (int s = 0; s < 2; ++s) {
      int wg = (b0 >> 4) + m2 * 2 + s;
      u32t lo = f2bf(acc[s][p][0] + bv) | (f2bf(acc[s][p][1] + bv) << 16);
      u32t hi = f2bf(acc[s][p][2] + bv) | (f2bf(acc[s][p][3] + bv) << 16);
      size_t off = (gate == 2)
          ? (size_t)t * 16384 + wg * 1024 + nb * 64 + lane
          : (size_t)t * 32768 + wg * 1024 + nb * 64 + lane;
      u32x2 vv; vv[0] = lo; vv[1] = hi;
      ((u32x2*)op)[off] = vv;
    }
  }
}

// ---------------------------------------------------------------------------
// Fused scan + out. Blocks 0..15: scan producers (one 16-row slice each,
// 8 waves, publish progress every 16 steps). Blocks 16..127: consumers,
// each strided over the 4096 (t,quarter) out-tiles, gated on progress>=t+1.
// ---------------------------------------------------------------------------
#define OFFSW(row, colx2) (((row) * 512 + (colx2)) ^ (((row) & 7) << 4))
#define LDA_HB(ks) (*(const s16x8*)((char*)hb + ((aoff + (ks) * 64) ^ asw)))
#define LDA_RH(ks) (*(const s16x8*)((char*)rh + ((aoff + (ks) * 64) ^ asw)))
#define ZLOAD(buf, ks) do { buf[0] = pz[(ks) * 64]; buf[1] = pz[(ks) * 64 + 512]; } while (0)
#define G1_STEP(buf, ks) do { s16x8 a_ = LDA_HB(ks); \
    ar0 = MF(a_, whr_r[0][ks], ar0); ar1 = MF(a_, whr_r[1][ks], ar1); \
    az0 = MF(a_, buf[0], az0);       az1 = MF(a_, buf[1], az1); } while (0)

__global__ __launch_bounds__(512, 2) void gru_fused(
    const float* __restrict__ h0, const u16t* __restrict__ wpack,
    const u16t* __restrict__ xr_p, const u16t* __restrict__ xz_p,
    const u16t* __restrict__ xh_p, u16t* __restrict__ cand_w,
    const u16t* __restrict__ cand_r, float* __restrict__ hout,
    int* __restrict__ prog, const float* __restrict__ bout,
    float* __restrict__ out) {
  __shared__ __align__(128) u16t smem[16384];   // 32 KB
  const int tid = threadIdx.x, lane = tid & 63, w = tid >> 6;
  const int bid = blockIdx.x;

  if (bid < 16) {
    // ======================= scan producer =======================
    u16t* hb = smem;
    u16t* rh = smem + 4096;
    const int wg = bid;
    const int rlo = (lane >> 4) * 4;
    const int cA = w * 32 + (lane & 15);

    float hr_[2][4];
#pragma unroll
    for (int c = 0; c < 2; ++c)
#pragma unroll
      for (int j = 0; j < 4; ++j)
        hr_[c][j] = h0[(size_t)(wg * 16 + rlo + j) * 256 + cA + c * 16];
#pragma unroll
    for (int c = 0; c < 2; ++c)
#pragma unroll
      for (int j = 0; j < 4; ++j)
        *(u16t*)((char*)hb + OFFSW(rlo + j, (cA + c * 16) * 2)) = (u16t)f2bf(hr_[c][j]);
    __syncthreads();

    const s16x8* pz = (const s16x8*)wpack + 4 * 8192 + w * 1024 + lane;
    const int aoff = (lane & 15) * 512 + (lane >> 4) * 16;
    const int asw = (lane & 7) << 4;

    s16x8 whr_r[2][8], whh_r[2][8];
    {
      const s16x8* prw = (const s16x8*)wpack + 3 * 8192;
      const s16x8* phw = (const s16x8*)wpack + 5 * 8192;
#pragma unroll
      for (int c = 0; c < 2; ++c)
#pragma unroll
        for (int ks = 0; ks < 8; ++ks) {
          int fo = ((2 * w + c) * 8 + ks) * 64 + lane;
          whr_r[c][ks] = prw[fo]; PIN(whr_r[c][ks]);
          whh_r[c][ks] = phw[fo]; PIN(whh_r[c][ks]);
        }
    }

    const size_t xoffRZ = (size_t)wg * 1024 + w * 128 + lane;  // u32x2, per-t 32768
    const size_t xoffH  = (size_t)wg * 1024 + w * 128 + lane;  // u32x2, per-t 16384
    const u32x2* PXR = (const u32x2*)xr_p;
    const u32x2* PXZ = (const u32x2*)xz_p;
    const u32x2* PXH = (const u32x2*)xh_p;
    u32x2* SXH = (u32x2*)cand_w;

    u32x2 vxr0 = PXR[xoffRZ], vxr1 = PXR[xoffRZ + 64];
    u32x2 vxz0 = PXZ[xoffRZ], vxz1 = PXZ[xoffRZ + 64];
    u32x2 vxh0 = PXH[xoffH],  vxh1 = PXH[xoffH + 64];

    s16x8 bA[2], bB[2];
    ZLOAD(bA, 0);
    ZLOAD(bB, 1);

    for (int t = 0; t < 1024; ++t) {
      f32x4 ar0, ar1, az0, az1;
      ar0[0] = lo_f(vxr0[0]); ar0[1] = hi_f(vxr0[0]); ar0[2] = lo_f(vxr0[1]); ar0[3] = hi_f(vxr0[1]);
      ar1[0] = lo_f(vxr1[0]); ar1[1] = hi_f(vxr1[0]); ar1[2] = lo_f(vxr1[1]); ar1[3] = hi_f(vxr1[1]);
      az0[0] = lo_f(vxz0[0]); az0[1] = hi_f(vxz0[0]); az0[2] = lo_f(vxz0[1]); az0[3] = hi_f(vxz0[1]);
      az1[0] = lo_f(vxz1[0]); az1[1] = hi_f(vxz1[0]); az1[2] = lo_f(vxz1[1]); az1[3] = hi_f(vxz1[1]);

      G1_STEP(bA, 0); ZLOAD(bA, 2);
      G1_STEP(bB, 1); ZLOAD(bB, 3);
      G1_STEP(bA, 2); ZLOAD(bA, 4);
      G1_STEP(bB, 3); ZLOAD(bB, 5);
      G1_STEP(bA, 4); ZLOAD(bA, 6);
      G1_STEP(bB, 5); ZLOAD(bB, 7);
      G1_STEP(bA, 6);
      G1_STEP(bB, 7);

      float r_[2][4];
      r_[0][0] = sigm2(ar0[0]); r_[0][1] = sigm2(ar0[1]); r_[0][2] = sigm2(ar0[2]); r_[0][3] = sigm2(ar0[3]);
      r_[1][0] = sigm2(ar1[0]); r_[1][1] = sigm2(ar1[1]); r_[1][2] = sigm2(ar1[2]); r_[1][3] = sigm2(ar1[3]);

#pragma unroll
      for (int c = 0; c < 2; ++c) {
        u32t p01 = cvtpk(r_[c][0] * hr_[c][0], r_[c][1] * hr_[c][1]);
        u32t p23 = cvtpk(r_[c][2] * hr_[c][2], r_[c][3] * hr_[c][3]);
        *(u16t*)((char*)rh + OFFSW(rlo + 0, (cA + c * 16) * 2)) = (u16t)p01;
        *(u16t*)((char*)rh + OFFSW(rlo + 1, (cA + c * 16) * 2)) = (u16t)(p01 >> 16);
        *(u16t*)((char*)rh + OFFSW(rlo + 2, (cA + c * 16) * 2)) = (u16t)p23;
        *(u16t*)((char*)rh + OFFSW(rlo + 3, (cA + c * 16) * 2)) = (u16t)(p23 >> 16);
      }
      BAR_LDS();

      float z_[2][4];
      z_[0][0] = sigm2(az0[0]); z_[0][1] = sigm2(az0[1]); z_[0][2] = sigm2(az0[2]); z_[0][3] = sigm2(az0[3]);
      z_[1][0] = sigm2(az1[0]); z_[1][1] = sigm2(az1[1]); z_[1][2] = sigm2(az1[2]); z_[1][3] = sigm2(az1[3]);

      f32x4 ac0, ac1;
      ac0[0] = lo_f(vxh0[0]); ac0[1] = hi_f(vxh0[0]); ac0[2] = lo_f(vxh0[1]); ac0[3] = hi_f(vxh0[1]);
      ac1[0] = lo_f(vxh1[0]); ac1[1] = hi_f(vxh1[0]); ac1[2] = lo_f(vxh1[1]); ac1[3] = hi_f(vxh1[1]);

      {  // reload x regs for t+1
        int tn = t < 1023 ? t + 1 : t;
        size_t oRZ = xoffRZ + (size_t)tn * 32768;
        size_t oH  = xoffH + (size_t)tn * 16384;
        vxr0 = PXR[oRZ]; vxr1 = PXR[oRZ + 64];
        vxz0 = PXZ[oRZ]; vxz1 = PXZ[oRZ + 64];
        vxh0 = PXH[oH];  vxh1 = PXH[oH + 64];
      }

#pragma unroll
      for (int ks = 0; ks < 8; ++ks) {
        s16x8 a_ = LDA_RH(ks);
        ac0 = MF(a_, whh_r[0][ks], ac0);
        ac1 = MF(a_, whh_r[1][ks], ac1);
      }

      float cd[2][4];
      cd[0][0] = tanh2(ac0[0]); cd[0][1] = tanh2(ac0[1]); cd[0][2] = tanh2(ac0[2]); cd[0][3] = tanh2(ac0[3]);
      cd[1][0] = tanh2(ac1[0]); cd[1][1] = tanh2(ac1[1]); cd[1][2] = tanh2(ac1[2]); cd[1][3] = tanh2(ac1[3]);

      size_t ocur = xoffH + (size_t)t * 16384;
      u32x2 s0, s1;
      s0[0] = cvtpk(cd[0][0], cd[0][1]); s0[1] = cvtpk(cd[0][2], cd[0][3]);
      s1[0] = cvtpk(cd[1][0], cd[1][1]); s1[1] = cvtpk(cd[1][2], cd[1][3]);
      SXH[ocur] = s0;
      SXH[ocur + 64] = s1;

#pragma unroll
      for (int c = 0; c < 2; ++c) {
#pragma unroll
        for (int j = 0; j < 4; ++j)
          hr_[c][j] = fmaf(z_[c][j], hr_[c][j] - cd[c][j], cd[c][j]);
        u32t p01 = cvtpk(hr_[c][0], hr_[c][1]);
        u32t p23 = cvtpk(hr_[c][2], hr_[c][3]);
        *(u16t*)((char*)hb + OFFSW(rlo + 0, (cA + c * 16) * 2)) = (u16t)p01;
        *(u16t*)((char*)hb + OFFSW(rlo + 1, (cA + c * 16) * 2)) = (u16t)(p01 >> 16);
        *(u16t*)((char*)hb + OFFSW(rlo + 2, (cA + c * 16) * 2)) = (u16t)p23;
        *(u16t*)((char*)hb + OFFSW(rlo + 3, (cA + c * 16) * 2)) = (u16t)(p23 >> 16);
      }

      ZLOAD(bA, 0);
      ZLOAD(bB, 1);
      BAR_LDS();

      // publish completed-step count every 16 steps (incl. t=1023 -> 1024)
      if ((t & 15) == 15) {
        __threadfence();          // drain stores + L2 writeback (device scope)
        __syncthreads();
        if (tid == 0)
          __hip_atomic_store(prog + wg, t + 1, __ATOMIC_RELAXED,
                             __HIP_MEMORY_SCOPE_AGENT);
      }
    }
#pragma unroll
    for (int c = 0; c < 2; ++c)
#pragma unroll
      for (int j = 0; j < 4; ++j)
        hout[(size_t)(wg * 16 + rlo + j) * 256 + cA + c * 16] = hr_[c][j];

  } else {
    // ======================= out consumer =======================
    u16t* cm = smem;
    const int cid = bid - 16;                 // 0..NCONS-1
    const s16x8* wo = (const s16x8*)wpack + 6 * 8192;
    const int mt = w & 3, nbs = (w >> 2) * 8;
    const int arow = mt * 16 + (lane & 15);
    const int abase = arow * 512 + (lane >> 4) * 16;
    const int asw = (lane & 7) << 4;
    const f32x4 Z = {0.f, 0.f, 0.f, 0.f};
    int lastmn = 0;

    for (int tile = cid; tile < 4096; tile += NCONS) {
      const int t = tile >> 2, q = tile & 3;
      const int need = t + 1;
      if (lastmn < need) {
        if (tid == 0) {
          int mn;
          for (;;) {
            mn = 1 << 30;
#pragma unroll
            for (int s = 0; s < 16; ++s)
              mn = min(mn, __hip_atomic_load(prog + s, __ATOMIC_RELAXED,
                                             __HIP_MEMORY_SCOPE_AGENT));
            if (mn >= need) break;
            __builtin_amdgcn_s_sleep(8);
            __builtin_amdgcn_s_sleep(8);
            __builtin_amdgcn_s_sleep(8);
            __builtin_amdgcn_s_sleep(8);
          }
          *(int*)cm = mn;
        }
        __syncthreads();
        lastmn = *(volatile int*)cm;
        __syncthreads();
      }
      // stage cand quarter [64][256] bf16 into swizzled LDS
      const u32x2* src = (const u32x2*)cand_r + ((size_t)t * 16 + q * 4) * 1024;
#pragma unroll
      for (int it = 0; it < 8; ++it) {
        int i = it * 512 + tid;
        u32x2 v = src[i];
        int wg_l = i >> 10, nb = (i >> 6) & 15, ls = i & 63;
        int brow = wg_l * 16 + (ls >> 4) * 4;
        int hc2 = (nb * 16 + (ls & 15)) * 2;
        u16t ev[4] = {(u16t)(v[0] & 0xffff), (u16t)(v[0] >> 16),
                      (u16t)(v[1] & 0xffff), (u16t)(v[1] >> 16)};
#pragma unroll
        for (int j = 0; j < 4; ++j)
          *(u16t*)((char*)cm + OFFSW(brow + j, hc2)) = ev[j];
      }
      __syncthreads();
      f32x4 acc[8] = {Z, Z, Z, Z, Z, Z, Z, Z};
#pragma unroll
      for (int ks = 0; ks < 8; ++ks) {
        s16x8 a = *(const s16x8*)((char*)cm + ((abase + ks * 64) ^ asw));
#pragma unroll
        for (int p = 0; p < 8; ++p)
          acc[p] = MF(a, wo[((nbs + p) * 8 + ks) * 64 + lane], acc[p]);
      }
#pragma unroll
      for (int p = 0; p < 8; ++p) {
        int col = (nbs + p) * 16 + (lane & 15);
        float bv = bout[col];
        size_t rb = (size_t)t * 256 + q * 64 + mt * 16 + (lane >> 4) * 4;
#pragma unroll
        for (int j = 0; j < 4; ++j)
          out[(rb + j) * 256 + col] = acc[p][j] + bv;
      }
      __syncthreads();
    }
  }
}

extern "C" void kernel_launch(void* const* d_in, const int* in_sizes, int n_in,
                              void* d_out, int out_size, void* d_ws, size_t ws_size,
                              hipStream_t stream) {
  const float* x    = (const float*)d_in[0];
  const float* h0   = (const float*)d_in[1];
  const float* wxr  = (const float*)d_in[2];
  const float* whr  = (const float*)d_in[3];
  const float* br   = (const float*)d_in[4];
  const float* wxz  = (const float*)d_in[5];
  const float* whz  = (const float*)d_in[6];
  const float* bz   = (const float*)d_in[7];
  const float* wxh  = (const float*)d_in[8];
  const float* whh  = (const float*)d_in[9];
  const float* bh   = (const float*)d_in[10];
  const float* wout = (const float*)d_in[11];
  const float* bout = (const float*)d_in[12];

  float* out  = (float*)d_out;
  u16t* wpack = (u16t*)d_ws;                               // 896 KB
  int*  prog  = (int*)((char*)d_ws + 917504);              // 64 B
  u16t* xh_p  = (u16t*)((char*)d_ws + (1u << 20));         // 128 MB (cand in-place)
  u16t* xr_p  = (u16t*)d_out;                              // interleaved block base
  u16t* xz_p  = (u16t*)d_out + 65536;                      // +128 KB within block
  float* hout = (float*)((char*)d_out + 268435456ull);     // h_final slot

  pack_w<<<1792, 256, 0, stream>>>(wxr, wxz, wxh, whr, whz, whh, wout, wpack, prog);
  gru_xproj<<<4096, 512, 0, stream>>>(x, wpack, br, bz, bh, xr_p, xz_p, xh_p);
  gru_fused<<<16 + NCONS, 512, 0, stream>>>(h0, wpack, xr_p, xz_p, xh_p,
                                            xh_p, xh_p, hout, prog, bout, out);
}

// Round 11
// 2441.441 us; speedup vs baseline: 1.1354x; 1.1354x over previous
//
#include <hip/hip_runtime.h>

// GRU: T=1024, B=256, I=H=O=256, fp32 in/out, bf16 MFMA internally.
// d_out layout: outs [T*B][O] fp32 then h_final [B][H] fp32.
// R1: LDS-only barriers. R2: VALU diet. R4: whr+whh AGPR-resident (PINned),
// whz L2-streamed via dbuf. R6/R7: log2e folding. R8: xproj B-reuse.
// R9: producer/consumer fusion (16 scan blocks + 112 consumers, progress
//     atomics, xr/xz interleaved per t so out[t] is safe at progress>=t+1).
//     Regressed: __threadfence = buffer_wbl2 flushed whole dirty L2 (incl.
//     consumers' out lines) 64x/producer; consumer streaming evicted whz.
// R10: coherence protocol swap. Producer cand stores are agent-scope relaxed
//     atomic stores (sc-bits, visible at coherent point on vmcnt retire) ->
//     publication needs only __syncthreads (vmcnt drain) + relaxed atomic;
//     NO wbl2. Consumers use non-temporal loads/stores (evict-first) so
//     their streaming does not thrash producers' whz L2 lines.

typedef unsigned short u16t;
typedef unsigned int   u32t;
typedef unsigned long long u64t;
typedef short  s16x8 __attribute__((ext_vector_type(8)));
typedef float  f32x4 __attribute__((ext_vector_type(4)));
typedef float  f32v4 __attribute__((ext_vector_type(4)));
typedef u32t   u32x2 __attribute__((ext_vector_type(2)));

#define L2E 1.4426950408889634f
#define NCONS 112

// LDS-only barrier: order ds ops, leave vmcnt in flight.
#define BAR_LDS() asm volatile("s_waitcnt lgkmcnt(0)\n\ts_barrier" ::: "memory")
// Pin a value in VGPRs/AGPRs: opaque to the optimizer, no remat.
#define PIN(v) asm volatile("" : "+v"(v))

__device__ __forceinline__ float lo_f(u32t u) {
  return __builtin_bit_cast(float, u << 16);
}
__device__ __forceinline__ float hi_f(u32t u) {
  return __builtin_bit_cast(float, u & 0xffff0000u);
}
__device__ __forceinline__ u32t f2bf(float f) {  // round-to-nearest-even
  u32t u = __builtin_bit_cast(u32t, f);
  return (u + 0x7fffu + ((u >> 16) & 1u)) >> 16;
}
__device__ __forceinline__ u32t cvtpk(float lo, float hi) {  // 2xbf16 RNE pack
  u32t r;
  asm("v_cvt_pk_bf16_f32 %0, %1, %2" : "=v"(r) : "v"(lo), "v"(hi));
  return r;
}
__device__ __forceinline__ f32x4 MF(s16x8 a, s16x8 b, f32x4 c) {
  return __builtin_amdgcn_mfma_f32_16x16x32_bf16(a, b, c, 0, 0, 0);
}
// y = x*log2e folded: sigma(x) = 1/(1+2^-y)
__device__ __forceinline__ float sigm2(float y) {
  return __builtin_amdgcn_rcpf(1.0f + __builtin_amdgcn_exp2f(-y));
}
// y = x*2*log2e folded: tanh(x) = 1 - 2/(2^y + 1)
__device__ __forceinline__ float tanh2(float y) {
  return fmaf(-2.0f, __builtin_amdgcn_rcpf(__builtin_amdgcn_exp2f(y) + 1.0f), 1.0f);
}

// ---------------------------------------------------------------------------
// Pack 7 weight matrices -> bf16 MFMA-B fragments, pre-scaled (log2e folds).
// Also zeroes the 16-slot progress array (block 0).
// ---------------------------------------------------------------------------
__global__ void pack_w(const float* __restrict__ wxr, const float* __restrict__ wxz,
                       const float* __restrict__ wxh, const float* __restrict__ whr,
                       const float* __restrict__ whz, const float* __restrict__ whh,
                       const float* __restrict__ wout, u16t* __restrict__ dst,
                       int* __restrict__ prog) {
  if (blockIdx.x == 0 && threadIdx.x < 16) prog[threadIdx.x] = 0;
  int e = blockIdx.x * 256 + threadIdx.x;     // [0, 7*65536)
  int mat = e >> 16, i = e & 65535;
  const float* src = mat == 0 ? wxr : mat == 1 ? wxz : mat == 2 ? wxh
                   : mat == 3 ? whr : mat == 4 ? whz : mat == 5 ? whh : wout;
  float sc = (mat == 2 || mat == 5) ? 2.0f * L2E : (mat == 6 ? 1.0f : L2E);
  int j = i & 7, lane = (i >> 3) & 63, ks = (i >> 9) & 7, nb = i >> 12;
  int k = ks * 32 + (lane >> 4) * 8 + j;
  int n = nb * 16 + (lane & 15);
  dst[e] = (u16t)f2bf(src[k * 256 + n] * sc);
}

// ---------------------------------------------------------------------------
// Phase 1: xg = x @ Wxg + bg (pre-scaled), bf16 C-frag-packed.
// xr/xz interleaved per t: u32x2 idx = t*32768 + wg*1024 + nb*64 + lane
// (xr at block base, xz at base+16384). xh keeps stride 16384 (in d_ws).
// ---------------------------------------------------------------------------
__global__ __launch_bounds__(512, 2) void gru_xproj(
    const float* __restrict__ x, const u16t* __restrict__ wpack,
    const float* __restrict__ br, const float* __restrict__ bz,
    const float* __restrict__ bh,
    u16t* __restrict__ xr_p, u16t* __restrict__ xz_p, u16t* __restrict__ xh_p) {
  __shared__ __align__(128) u16t xt[16384];   // [64][256] bf16, XOR-swizzled
  const int tid = threadIdx.x, bid = blockIdx.x;
  const int t = bid >> 2, b0 = (bid & 3) * 64;
  const float* xrow = x + ((size_t)t * 256 + b0) * 256;
#pragma unroll
  for (int c = 0; c < 8; ++c) {
    int f4 = c * 512 + tid;                   // [0,4096) float4s
    f32v4 v = ((const f32v4*)xrow)[f4];
    u32t lo = f2bf(v[0]) | (f2bf(v[1]) << 16);
    u32t hi = f2bf(v[2]) | (f2bf(v[3]) << 16);
    int row = f4 >> 6, c8 = (f4 & 63) * 8;
    int off = (row * 512 + c8) ^ ((row & 7) << 4);
    u32x2 vv; vv[0] = lo; vv[1] = hi;
    *(u32x2*)((char*)xt + off) = vv;
  }
  __syncthreads();
  const int lane = tid & 63, w = tid >> 6;
  const int m2 = w & 1, cg = w >> 1;          // rows m2*32+..; combos cg*12+..
  const int arow = m2 * 32 + (lane & 15);     // s=0 row; s=1 -> +16
  const int abase = arow * 512 + (lane >> 4) * 16;
  const int asw = (lane & 7) << 4;
  const f32x4 Z = {0.f, 0.f, 0.f, 0.f};
  f32x4 acc[2][12];
#pragma unroll
  for (int s = 0; s < 2; ++s)
#pragma unroll
    for (int p = 0; p < 12; ++p) acc[s][p] = Z;
#pragma unroll
  for (int ks = 0; ks < 8; ++ks) {
    s16x8 a0 = *(const s16x8*)((char*)xt + ((abase + ks * 64) ^ asw));
    s16x8 a1 = *(const s16x8*)((char*)xt + ((abase + 16 * 512 + ks * 64) ^ asw));
#pragma unroll
    for (int p = 0; p < 12; ++p) {
      int pj = cg * 12 + p;
      int gate = pj >> 4, nb = pj & 15;
      const s16x8* wb = (const s16x8*)wpack + gate * 8192;
      s16x8 b = wb[(nb * 8 + ks) * 64 + lane];
      acc[0][p] = MF(a0, b, acc[0][p]);
      acc[1][p] = MF(a1, b, acc[1][p]);
    }
  }
#pragma unroll
  for (int p = 0; p < 12; ++p) {
    int pj = cg * 12 + p;
    int gate = pj >> 4, nb = pj & 15;
    const float* bp = gate == 0 ? br : gate == 1 ? bz : bh;
    float bs = (gate == 2) ? 2.0f * L2E : L2E;
    float bv = bp[nb * 16 + (lane & 15)] * bs;
    u16t* op = gate == 0 ? xr_p : gate == 1 ? xz_p : xh_p;
#pragma unroll
    for (int s = 0; s < 2; ++s) {
      int wg = (b0 >> 4) + m2 * 2 + s;
      u32t lo = f2bf(acc[s][p][0] + bv) | (f2bf(acc[s][p][1] + bv) << 16);
      u32t hi = f2bf(acc[s][p][2] + bv) | (f2bf(acc[s][p][3] + bv) << 16);
      size_t off = (gate == 2)
          ? (size_t)t * 16384 + wg * 1024 + nb * 64 + lane
          : (size_t)t * 32768 + wg * 1024 + nb * 64 + lane;
      u32x2 vv; vv[0] = lo; vv[1] = hi;
      ((u32x2*)op)[off] = vv;
    }
  }
}

// ---------------------------------------------------------------------------
// Fused scan + out. Blocks 0..15: scan producers (publish progress every 16
// steps via agent-scope stores, NO wbl2). Blocks 16..127: consumers (nt
// loads/stores), gated on progress >= t+1.
// ---------------------------------------------------------------------------
#define OFFSW(row, colx2) (((row) * 512 + (colx2)) ^ (((row) & 7) << 4))
#define LDA_HB(ks) (*(const s16x8*)((char*)hb + ((aoff + (ks) * 64) ^ asw)))
#define LDA_RH(ks) (*(const s16x8*)((char*)rh + ((aoff + (ks) * 64) ^ asw)))
#define ZLOAD(buf, ks) do { buf[0] = pz[(ks) * 64]; buf[1] = pz[(ks) * 64 + 512]; } while (0)
#define G1_STEP(buf, ks) do { s16x8 a_ = LDA_HB(ks); \
    ar0 = MF(a_, whr_r[0][ks], ar0); ar1 = MF(a_, whr_r[1][ks], ar1); \
    az0 = MF(a_, buf[0], az0);       az1 = MF(a_, buf[1], az1); } while (0)

__global__ __launch_bounds__(512, 2) void gru_fused(
    const float* __restrict__ h0, const u16t* __restrict__ wpack,
    const u16t* __restrict__ xr_p, const u16t* __restrict__ xz_p,
    const u16t* __restrict__ xh_p, u16t* __restrict__ cand_w,
    const u16t* __restrict__ cand_r, float* __restrict__ hout,
    int* __restrict__ prog, const float* __restrict__ bout,
    float* __restrict__ out) {
  __shared__ __align__(128) u16t smem[16384];   // 32 KB
  const int tid = threadIdx.x, lane = tid & 63, w = tid >> 6;
  const int bid = blockIdx.x;

  if (bid < 16) {
    // ======================= scan producer =======================
    u16t* hb = smem;
    u16t* rh = smem + 4096;
    const int wg = bid;
    const int rlo = (lane >> 4) * 4;
    const int cA = w * 32 + (lane & 15);

    float hr_[2][4];
#pragma unroll
    for (int c = 0; c < 2; ++c)
#pragma unroll
      for (int j = 0; j < 4; ++j)
        hr_[c][j] = h0[(size_t)(wg * 16 + rlo + j) * 256 + cA + c * 16];
#pragma unroll
    for (int c = 0; c < 2; ++c)
#pragma unroll
      for (int j = 0; j < 4; ++j)
        *(u16t*)((char*)hb + OFFSW(rlo + j, (cA + c * 16) * 2)) = (u16t)f2bf(hr_[c][j]);
    __syncthreads();

    const s16x8* pz = (const s16x8*)wpack + 4 * 8192 + w * 1024 + lane;
    const int aoff = (lane & 15) * 512 + (lane >> 4) * 16;
    const int asw = (lane & 7) << 4;

    s16x8 whr_r[2][8], whh_r[2][8];
    {
      const s16x8* prw = (const s16x8*)wpack + 3 * 8192;
      const s16x8* phw = (const s16x8*)wpack + 5 * 8192;
#pragma unroll
      for (int c = 0; c < 2; ++c)
#pragma unroll
        for (int ks = 0; ks < 8; ++ks) {
          int fo = ((2 * w + c) * 8 + ks) * 64 + lane;
          whr_r[c][ks] = prw[fo]; PIN(whr_r[c][ks]);
          whh_r[c][ks] = phw[fo]; PIN(whh_r[c][ks]);
        }
    }

    const size_t xoffRZ = (size_t)wg * 1024 + w * 128 + lane;  // u32x2, per-t 32768
    const size_t xoffH  = (size_t)wg * 1024 + w * 128 + lane;  // u32x2, per-t 16384
    const u32x2* PXR = (const u32x2*)xr_p;
    const u32x2* PXZ = (const u32x2*)xz_p;
    const u32x2* PXH = (const u32x2*)xh_p;
    u32x2* SXH = (u32x2*)cand_w;

    u32x2 vxr0 = PXR[xoffRZ], vxr1 = PXR[xoffRZ + 64];
    u32x2 vxz0 = PXZ[xoffRZ], vxz1 = PXZ[xoffRZ + 64];
    u32x2 vxh0 = PXH[xoffH],  vxh1 = PXH[xoffH + 64];

    s16x8 bA[2], bB[2];
    ZLOAD(bA, 0);
    ZLOAD(bB, 1);

    for (int t = 0; t < 1024; ++t) {
      f32x4 ar0, ar1, az0, az1;
      ar0[0] = lo_f(vxr0[0]); ar0[1] = hi_f(vxr0[0]); ar0[2] = lo_f(vxr0[1]); ar0[3] = hi_f(vxr0[1]);
      ar1[0] = lo_f(vxr1[0]); ar1[1] = hi_f(vxr1[0]); ar1[2] = lo_f(vxr1[1]); ar1[3] = hi_f(vxr1[1]);
      az0[0] = lo_f(vxz0[0]); az0[1] = hi_f(vxz0[0]); az0[2] = lo_f(vxz0[1]); az0[3] = hi_f(vxz0[1]);
      az1[0] = lo_f(vxz1[0]); az1[1] = hi_f(vxz1[0]); az1[2] = lo_f(vxz1[1]); az1[3] = hi_f(vxz1[1]);

      G1_STEP(bA, 0); ZLOAD(bA, 2);
      G1_STEP(bB, 1); ZLOAD(bB, 3);
      G1_STEP(bA, 2); ZLOAD(bA, 4);
      G1_STEP(bB, 3); ZLOAD(bB, 5);
      G1_STEP(bA, 4); ZLOAD(bA, 6);
      G1_STEP(bB, 5); ZLOAD(bB, 7);
      G1_STEP(bA, 6);
      G1_STEP(bB, 7);

      float r_[2][4];
      r_[0][0] = sigm2(ar0[0]); r_[0][1] = sigm2(ar0[1]); r_[0][2] = sigm2(ar0[2]); r_[0][3] = sigm2(ar0[3]);
      r_[1][0] = sigm2(ar1[0]); r_[1][1] = sigm2(ar1[1]); r_[1][2] = sigm2(ar1[2]); r_[1][3] = sigm2(ar1[3]);

#pragma unroll
      for (int c = 0; c < 2; ++c) {
        u32t p01 = cvtpk(r_[c][0] * hr_[c][0], r_[c][1] * hr_[c][1]);
        u32t p23 = cvtpk(r_[c][2] * hr_[c][2], r_[c][3] * hr_[c][3]);
        *(u16t*)((char*)rh + OFFSW(rlo + 0, (cA + c * 16) * 2)) = (u16t)p01;
        *(u16t*)((char*)rh + OFFSW(rlo + 1, (cA + c * 16) * 2)) = (u16t)(p01 >> 16);
        *(u16t*)((char*)rh + OFFSW(rlo + 2, (cA + c * 16) * 2)) = (u16t)p23;
        *(u16t*)((char*)rh + OFFSW(rlo + 3, (cA + c * 16) * 2)) = (u16t)(p23 >> 16);
      }
      BAR_LDS();

      float z_[2][4];
      z_[0][0] = sigm2(az0[0]); z_[0][1] = sigm2(az0[1]); z_[0][2] = sigm2(az0[2]); z_[0][3] = sigm2(az0[3]);
      z_[1][0] = sigm2(az1[0]); z_[1][1] = sigm2(az1[1]); z_[1][2] = sigm2(az1[2]); z_[1][3] = sigm2(az1[3]);

      f32x4 ac0, ac1;
      ac0[0] = lo_f(vxh0[0]); ac0[1] = hi_f(vxh0[0]); ac0[2] = lo_f(vxh0[1]); ac0[3] = hi_f(vxh0[1]);
      ac1[0] = lo_f(vxh1[0]); ac1[1] = hi_f(vxh1[0]); ac1[2] = lo_f(vxh1[1]); ac1[3] = hi_f(vxh1[1]);

      {  // reload x regs for t+1
        int tn = t < 1023 ? t + 1 : t;
        size_t oRZ = xoffRZ + (size_t)tn * 32768;
        size_t oH  = xoffH + (size_t)tn * 16384;
        vxr0 = PXR[oRZ]; vxr1 = PXR[oRZ + 64];
        vxz0 = PXZ[oRZ]; vxz1 = PXZ[oRZ + 64];
        vxh0 = PXH[oH];  vxh1 = PXH[oH + 64];
      }

#pragma unroll
      for (int ks = 0; ks < 8; ++ks) {
        s16x8 a_ = LDA_RH(ks);
        ac0 = MF(a_, whh_r[0][ks], ac0);
        ac1 = MF(a_, whh_r[1][ks], ac1);
      }

      float cd[2][4];
      cd[0][0] = tanh2(ac0[0]); cd[0][1] = tanh2(ac0[1]); cd[0][2] = tanh2(ac0[2]); cd[0][3] = tanh2(ac0[3]);
      cd[1][0] = tanh2(ac1[0]); cd[1][1] = tanh2(ac1[1]); cd[1][2] = tanh2(ac1[2]); cd[1][3] = tanh2(ac1[3]);

      // cand stores: agent-scope relaxed atomics (sc-bits, coherent-point
      // visible on vmcnt retire) -> no wbl2 needed at publication.
      size_t ocur = xoffH + (size_t)t * 16384;
      u32x2 s0, s1;
      s0[0] = cvtpk(cd[0][0], cd[0][1]); s0[1] = cvtpk(cd[0][2], cd[0][3]);
      s1[0] = cvtpk(cd[1][0], cd[1][1]); s1[1] = cvtpk(cd[1][2], cd[1][3]);
      __hip_atomic_store((u64t*)(SXH + ocur), __builtin_bit_cast(u64t, s0),
                         __ATOMIC_RELAXED, __HIP_MEMORY_SCOPE_AGENT);
      __hip_atomic_store((u64t*)(SXH + ocur + 64), __builtin_bit_cast(u64t, s1),
                         __ATOMIC_RELAXED, __HIP_MEMORY_SCOPE_AGENT);

#pragma unroll
      for (int c = 0; c < 2; ++c) {
#pragma unroll
        for (int j = 0; j < 4; ++j)
          hr_[c][j] = fmaf(z_[c][j], hr_[c][j] - cd[c][j], cd[c][j]);
        u32t p01 = cvtpk(hr_[c][0], hr_[c][1]);
        u32t p23 = cvtpk(hr_[c][2], hr_[c][3]);
        *(u16t*)((char*)hb + OFFSW(rlo + 0, (cA + c * 16) * 2)) = (u16t)p01;
        *(u16t*)((char*)hb + OFFSW(rlo + 1, (cA + c * 16) * 2)) = (u16t)(p01 >> 16);
        *(u16t*)((char*)hb + OFFSW(rlo + 2, (cA + c * 16) * 2)) = (u16t)p23;
        *(u16t*)((char*)hb + OFFSW(rlo + 3, (cA + c * 16) * 2)) = (u16t)(p23 >> 16);
      }

      ZLOAD(bA, 0);
      ZLOAD(bB, 1);
      BAR_LDS();

      // publish completed-step count every 16 steps: full __syncthreads
      // (drains every wave's vmcnt incl. the sc-stores) then relaxed store.
      if ((t & 15) == 15) {
        __syncthreads();
        if (tid == 0)
          __hip_atomic_store(prog + wg, t + 1, __ATOMIC_RELAXED,
                             __HIP_MEMORY_SCOPE_AGENT);
      }
    }
#pragma unroll
    for (int c = 0; c < 2; ++c)
#pragma unroll
      for (int j = 0; j < 4; ++j)
        hout[(size_t)(wg * 16 + rlo + j) * 256 + cA + c * 16] = hr_[c][j];

  } else {
    // ======================= out consumer =======================
    u16t* cm = smem;
    const int cid = bid - 16;                 // 0..NCONS-1
    const s16x8* wo = (const s16x8*)wpack + 6 * 8192;
    const int mt = w & 3, nbs = (w >> 2) * 8;
    const int arow = mt * 16 + (lane & 15);
    const int abase = arow * 512 + (lane >> 4) * 16;
    const int asw = (lane & 7) << 4;
    const f32x4 Z = {0.f, 0.f, 0.f, 0.f};
    int lastmn = 0;

    for (int tile = cid; tile < 4096; tile += NCONS) {
      const int t = tile >> 2, q = tile & 3;
      const int need = t + 1;
      if (lastmn < need) {
        if (tid == 0) {
          int mn;
          for (;;) {
            mn = 1 << 30;
#pragma unroll
            for (int s = 0; s < 16; ++s)
              mn = min(mn, __hip_atomic_load(prog + s, __ATOMIC_RELAXED,
                                             __HIP_MEMORY_SCOPE_AGENT));
            if (mn >= need) break;
            __builtin_amdgcn_s_sleep(8);
            __builtin_amdgcn_s_sleep(8);
            __builtin_amdgcn_s_sleep(8);
            __builtin_amdgcn_s_sleep(8);
          }
          *(int*)cm = mn;
        }
        __syncthreads();
        lastmn = *(volatile int*)cm;
        __syncthreads();
      }
      // stage cand quarter [64][256] bf16 into swizzled LDS (nt loads)
      const u32x2* src = (const u32x2*)cand_r + ((size_t)t * 16 + q * 4) * 1024;
#pragma unroll
      for (int it = 0; it < 8; ++it) {
        int i = it * 512 + tid;
        u32x2 v = __builtin_nontemporal_load(src + i);
        int wg_l = i >> 10, nb = (i >> 6) & 15, ls = i & 63;
        int brow = wg_l * 16 + (ls >> 4) * 4;
        int hc2 = (nb * 16 + (ls & 15)) * 2;
        u16t ev[4] = {(u16t)(v[0] & 0xffff), (u16t)(v[0] >> 16),
                      (u16t)(v[1] & 0xffff), (u16t)(v[1] >> 16)};
#pragma unroll
        for (int j = 0; j < 4; ++j)
          *(u16t*)((char*)cm + OFFSW(brow + j, hc2)) = ev[j];
      }
      __syncthreads();
      f32x4 acc[8] = {Z, Z, Z, Z, Z, Z, Z, Z};
#pragma unroll
      for (int ks = 0; ks < 8; ++ks) {
        s16x8 a = *(const s16x8*)((char*)cm + ((abase + ks * 64) ^ asw));
#pragma unroll
        for (int p = 0; p < 8; ++p)
          acc[p] = MF(a, wo[((nbs + p) * 8 + ks) * 64 + lane], acc[p]);
      }
#pragma unroll
      for (int p = 0; p < 8; ++p) {
        int col = (nbs + p) * 16 + (lane & 15);
        float bv = bout[col];
        size_t rb = (size_t)t * 256 + q * 64 + mt * 16 + (lane >> 4) * 4;
#pragma unroll
        for (int j = 0; j < 4; ++j)
          __builtin_nontemporal_store(acc[p][j] + bv, &out[(rb + j) * 256 + col]);
      }
      __syncthreads();
    }
  }
}

extern "C" void kernel_launch(void* const* d_in, const int* in_sizes, int n_in,
                              void* d_out, int out_size, void* d_ws, size_t ws_size,
                              hipStream_t stream) {
  const float* x    = (const float*)d_in[0];
  const float* h0   = (const float*)d_in[1];
  const float* wxr  = (const float*)d_in[2];
  const float* whr  = (const float*)d_in[3];
  const float* br   = (const float*)d_in[4];
  const float* wxz  = (const float*)d_in[5];
  const float* whz  = (const float*)d_in[6];
  const float* bz   = (const float*)d_in[7];
  const float* wxh  = (const float*)d_in[8];
  const float* whh  = (const float*)d_in[9];
  const float* bh   = (const float*)d_in[10];
  const float* wout = (const float*)d_in[11];
  const float* bout = (const float*)d_in[12];

  float* out  = (float*)d_out;
  u16t* wpack = (u16t*)d_ws;                               // 896 KB
  int*  prog  = (int*)((char*)d_ws + 917504);              // 64 B
  u16t* xh_p  = (u16t*)((char*)d_ws + (1u << 20));         // 128 MB (cand in-place)
  u16t* xr_p  = (u16t*)d_out;                              // interleaved block base
  u16t* xz_p  = (u16t*)d_out + 65536;                      // +128 KB within block
  float* hout = (float*)((char*)d_out + 268435456ull);     // h_final slot

  pack_w<<<1792, 256, 0, stream>>>(wxr, wxz, wxh, whr, whz, whh, wout, wpack, prog);
  gru_xproj<<<4096, 512, 0, stream>>>(x, wpack, br, bz, bh, xr_p, xz_p, xh_p);
  gru_fused<<<16 + NCONS, 512, 0, stream>>>(h0, wpack, xr_p, xz_p, xh_p,
                                            xh_p, xh_p, hout, prog, bout, out);
}

// Round 12
// 2215.578 us; speedup vs baseline: 1.2512x; 1.1019x over previous
//
#include <hip/hip_runtime.h>

// GRU: T=1024, B=256, I=H=O=256, fp32 in/out, bf16 MFMA internally.
// d_out layout: outs [T*B][O] fp32 then h_final [B][H] fp32.
// R1: LDS-only barriers. R2: VALU diet. R4: whr+whh AGPR-resident (PINned),
// whz L2-streamed via dbuf. R6/R7: log2e folding. R8: xproj B-reuse.
// R9/R10: producer/consumer fusion of gru_out with sc-store publication
//     (agent-scope relaxed atomics; __syncthreads drains vmcnt; no wbl2).
// R11: xproj folded into fused kernel as consumer PRE-PHASE. Consumers do
//     8192 xproj half-tiles (ascending t, acc[2][6]=48 VGPR to hold the
//     128V+128A budget), publishing coverage xprog[cid]=next_tile; scan
//     producers gate each 16-step chunk on min(xprog) >= 8*(t+17)+8.
//     Pace: xproj ~2.5 t/us vs scan 0.5 t/us (5x margin). cand staging in
//     out-phase uses agent-scope atomic loads (stale-L2 hazard: consumer's
//     own xproj-era line). No wait cycle: producers<-xprog<-consumers(free);
//     consumers<-prog<-producers(free).

typedef unsigned short u16t;
typedef unsigned int   u32t;
typedef unsigned long long u64t;
typedef short  s16x8 __attribute__((ext_vector_type(8)));
typedef float  f32x4 __attribute__((ext_vector_type(4)));
typedef float  f32v4 __attribute__((ext_vector_type(4)));
typedef u32t   u32x2 __attribute__((ext_vector_type(2)));

#define L2E 1.4426950408889634f
#define NCONS 112

// LDS-only barrier: order ds ops, leave vmcnt in flight.
#define BAR_LDS() asm volatile("s_waitcnt lgkmcnt(0)\n\ts_barrier" ::: "memory")
// Pin a value in VGPRs/AGPRs: opaque to the optimizer, no remat.
#define PIN(v) asm volatile("" : "+v"(v))

__device__ __forceinline__ float lo_f(u32t u) {
  return __builtin_bit_cast(float, u << 16);
}
__device__ __forceinline__ float hi_f(u32t u) {
  return __builtin_bit_cast(float, u & 0xffff0000u);
}
__device__ __forceinline__ u32t f2bf(float f) {  // round-to-nearest-even
  u32t u = __builtin_bit_cast(u32t, f);
  return (u + 0x7fffu + ((u >> 16) & 1u)) >> 16;
}
__device__ __forceinline__ u32t cvtpk(float lo, float hi) {  // 2xbf16 RNE pack
  u32t r;
  asm("v_cvt_pk_bf16_f32 %0, %1, %2" : "=v"(r) : "v"(lo), "v"(hi));
  return r;
}
__device__ __forceinline__ f32x4 MF(s16x8 a, s16x8 b, f32x4 c) {
  return __builtin_amdgcn_mfma_f32_16x16x32_bf16(a, b, c, 0, 0, 0);
}
// y = x*log2e folded: sigma(x) = 1/(1+2^-y)
__device__ __forceinline__ float sigm2(float y) {
  return __builtin_amdgcn_rcpf(1.0f + __builtin_amdgcn_exp2f(-y));
}
// y = x*2*log2e folded: tanh(x) = 1 - 2/(2^y + 1)
__device__ __forceinline__ float tanh2(float y) {
  return fmaf(-2.0f, __builtin_amdgcn_rcpf(__builtin_amdgcn_exp2f(y) + 1.0f), 1.0f);
}
__device__ __forceinline__ void st_agent(u32x2* p, u32x2 v) {
  __hip_atomic_store((u64t*)p, __builtin_bit_cast(u64t, v),
                     __ATOMIC_RELAXED, __HIP_MEMORY_SCOPE_AGENT);
}
__device__ __forceinline__ u32x2 ld_agent(const u32x2* p) {
  return __builtin_bit_cast(u32x2,
      __hip_atomic_load((const u64t*)p, __ATOMIC_RELAXED,
                        __HIP_MEMORY_SCOPE_AGENT));
}

// ---------------------------------------------------------------------------
// Pack 7 weight matrices -> bf16 MFMA-B fragments, pre-scaled (log2e folds).
// Also zeroes prog[0..15] (scan) and xprog[0..111] (xproj coverage).
// ---------------------------------------------------------------------------
__global__ void pack_w(const float* __restrict__ wxr, const float* __restrict__ wxz,
                       const float* __restrict__ wxh, const float* __restrict__ whr,
                       const float* __restrict__ whz, const float* __restrict__ whh,
                       const float* __restrict__ wout, u16t* __restrict__ dst,
                       int* __restrict__ prog) {
  if (blockIdx.x == 0 && threadIdx.x < 128) prog[threadIdx.x] = 0;
  int e = blockIdx.x * 256 + threadIdx.x;     // [0, 7*65536)
  int mat = e >> 16, i = e & 65535;
  const float* src = mat == 0 ? wxr : mat == 1 ? wxz : mat == 2 ? wxh
                   : mat == 3 ? whr : mat == 4 ? whz : mat == 5 ? whh : wout;
  float sc = (mat == 2 || mat == 5) ? 2.0f * L2E : (mat == 6 ? 1.0f : L2E);
  int j = i & 7, lane = (i >> 3) & 63, ks = (i >> 9) & 7, nb = i >> 12;
  int k = ks * 32 + (lane >> 4) * 8 + j;
  int n = nb * 16 + (lane & 15);
  dst[e] = (u16t)f2bf(src[k * 256 + n] * sc);
}

// ---------------------------------------------------------------------------
// Fused xproj + scan + out.
// Blocks 0..15: scan producers (gate on xproj coverage; publish prog/16 steps).
// Blocks 16..127: consumers — phase A: xproj half-tiles (sc-stores, publish
// coverage); phase B: out-tiles (gated on scan prog; atomic cand loads).
// xr/xz interleaved per t (u32x2: t*32768 + wg*1024 + nb*64 + lane; xz at
// +16384); xh stride 16384 in d_ws.
// ---------------------------------------------------------------------------
#define OFFSW(row, colx2) (((row) * 512 + (colx2)) ^ (((row) & 7) << 4))
#define LDA_HB(ks) (*(const s16x8*)((char*)hb + ((aoff + (ks) * 64) ^ asw)))
#define LDA_RH(ks) (*(const s16x8*)((char*)rh + ((aoff + (ks) * 64) ^ asw)))
#define ZLOAD(buf, ks) do { buf[0] = pz[(ks) * 64]; buf[1] = pz[(ks) * 64 + 512]; } while (0)
#define G1_STEP(buf, ks) do { s16x8 a_ = LDA_HB(ks); \
    ar0 = MF(a_, whr_r[0][ks], ar0); ar1 = MF(a_, whr_r[1][ks], ar1); \
    az0 = MF(a_, buf[0], az0);       az1 = MF(a_, buf[1], az1); } while (0)

__global__ __launch_bounds__(512, 2) void gru_fused(
    const float* __restrict__ x, const float* __restrict__ h0,
    const u16t* __restrict__ wpack,
    const float* __restrict__ br, const float* __restrict__ bz,
    const float* __restrict__ bh,
    u16t* __restrict__ xr_p, u16t* __restrict__ xz_p, u16t* __restrict__ xh_p,
    float* __restrict__ hout, int* __restrict__ prog,
    const float* __restrict__ bout, float* __restrict__ out) {
  __shared__ __align__(128) u16t smem[16384];   // 32 KB (+bcast slot below)
  __shared__ __align__(16) int bc[4];
  const int tid = threadIdx.x, lane = tid & 63, w = tid >> 6;
  const int bid = blockIdx.x;
  int* xprog = prog + 16;

  if (bid < 16) {
    // ======================= scan producer =======================
    u16t* hb = smem;
    u16t* rh = smem + 4096;
    const int wg = bid;
    const int rlo = (lane >> 4) * 4;
    const int cA = w * 32 + (lane & 15);

    float hr_[2][4];
#pragma unroll
    for (int c = 0; c < 2; ++c)
#pragma unroll
      for (int j = 0; j < 4; ++j)
        hr_[c][j] = h0[(size_t)(wg * 16 + rlo + j) * 256 + cA + c * 16];
#pragma unroll
    for (int c = 0; c < 2; ++c)
#pragma unroll
      for (int j = 0; j < 4; ++j)
        *(u16t*)((char*)hb + OFFSW(rlo + j, (cA + c * 16) * 2)) = (u16t)f2bf(hr_[c][j]);
    __syncthreads();

    const s16x8* pz = (const s16x8*)wpack + 4 * 8192 + w * 1024 + lane;
    const int aoff = (lane & 15) * 512 + (lane >> 4) * 16;
    const int asw = (lane & 7) << 4;

    s16x8 whr_r[2][8], whh_r[2][8];
    {
      const s16x8* prw = (const s16x8*)wpack + 3 * 8192;
      const s16x8* phw = (const s16x8*)wpack + 5 * 8192;
#pragma unroll
      for (int c = 0; c < 2; ++c)
#pragma unroll
        for (int ks = 0; ks < 8; ++ks) {
          int fo = ((2 * w + c) * 8 + ks) * 64 + lane;
          whr_r[c][ks] = prw[fo]; PIN(whr_r[c][ks]);
          whh_r[c][ks] = phw[fo]; PIN(whh_r[c][ks]);
        }
    }

    const size_t xoffRZ = (size_t)wg * 1024 + w * 128 + lane;  // u32x2, per-t 32768
    const size_t xoffH  = (size_t)wg * 1024 + w * 128 + lane;  // u32x2, per-t 16384
    const u32x2* PXR = (const u32x2*)xr_p;
    const u32x2* PXZ = (const u32x2*)xz_p;
    const u32x2* PXH = (const u32x2*)xh_p;
    u32x2* SXH = (u32x2*)xh_p;

    // --- pre-gate: xproj coverage for t in [0, 17] ---
    int Mcur = 0;
    {
      const int Mreq = 8 * 17 + 8;
      if (tid == 0) {
        int M;
        for (;;) {
          M = 1 << 30;
#pragma unroll 16
          for (int c2 = 0; c2 < NCONS; ++c2)
            M = min(M, __hip_atomic_load(xprog + c2, __ATOMIC_RELAXED,
                                         __HIP_MEMORY_SCOPE_AGENT));
          if (M >= Mreq) break;
          __builtin_amdgcn_s_sleep(8);
          __builtin_amdgcn_s_sleep(8);
        }
        bc[0] = M;
      }
      __syncthreads();
      Mcur = bc[0];
      __syncthreads();
    }

    u32x2 vxr0 = PXR[xoffRZ], vxr1 = PXR[xoffRZ + 64];
    u32x2 vxz0 = PXZ[xoffRZ], vxz1 = PXZ[xoffRZ + 64];
    u32x2 vxh0 = PXH[xoffH],  vxh1 = PXH[xoffH + 64];

    s16x8 bA[2], bB[2];
    ZLOAD(bA, 0);
    ZLOAD(bB, 1);

    for (int t = 0; t < 1024; ++t) {
      // chunk gate: xproj coverage through t+17
      if ((t & 15) == 0 && t > 0) {
        int treq = t + 17; if (treq > 1023) treq = 1023;
        int Mreq = 8 * treq + 8;
        if (Mcur < Mreq) {
          if (tid == 0) {
            int M;
            for (;;) {
              M = 1 << 30;
#pragma unroll 16
              for (int c2 = 0; c2 < NCONS; ++c2)
                M = min(M, __hip_atomic_load(xprog + c2, __ATOMIC_RELAXED,
                                             __HIP_MEMORY_SCOPE_AGENT));
              if (M >= Mreq) break;
              __builtin_amdgcn_s_sleep(8);
              __builtin_amdgcn_s_sleep(8);
            }
            bc[0] = M;
          }
          __syncthreads();
          Mcur = bc[0];
          __syncthreads();
        }
      }

      f32x4 ar0, ar1, az0, az1;
      ar0[0] = lo_f(vxr0[0]); ar0[1] = hi_f(vxr0[0]); ar0[2] = lo_f(vxr0[1]); ar0[3] = hi_f(vxr0[1]);
      ar1[0] = lo_f(vxr1[0]); ar1[1] = hi_f(vxr1[0]); ar1[2] = lo_f(vxr1[1]); ar1[3] = hi_f(vxr1[1]);
      az0[0] = lo_f(vxz0[0]); az0[1] = hi_f(vxz0[0]); az0[2] = lo_f(vxz0[1]); az0[3] = hi_f(vxz0[1]);
      az1[0] = lo_f(vxz1[0]); az1[1] = hi_f(vxz1[0]); az1[2] = lo_f(vxz1[1]); az1[3] = hi_f(vxz1[1]);

      G1_STEP(bA, 0); ZLOAD(bA, 2);
      G1_STEP(bB, 1); ZLOAD(bB, 3);
      G1_STEP(bA, 2); ZLOAD(bA, 4);
      G1_STEP(bB, 3); ZLOAD(bB, 5);
      G1_STEP(bA, 4); ZLOAD(bA, 6);
      G1_STEP(bB, 5); ZLOAD(bB, 7);
      G1_STEP(bA, 6);
      G1_STEP(bB, 7);

      float r_[2][4];
      r_[0][0] = sigm2(ar0[0]); r_[0][1] = sigm2(ar0[1]); r_[0][2] = sigm2(ar0[2]); r_[0][3] = sigm2(ar0[3]);
      r_[1][0] = sigm2(ar1[0]); r_[1][1] = sigm2(ar1[1]); r_[1][2] = sigm2(ar1[2]); r_[1][3] = sigm2(ar1[3]);

#pragma unroll
      for (int c = 0; c < 2; ++c) {
        u32t p01 = cvtpk(r_[c][0] * hr_[c][0], r_[c][1] * hr_[c][1]);
        u32t p23 = cvtpk(r_[c][2] * hr_[c][2], r_[c][3] * hr_[c][3]);
        *(u16t*)((char*)rh + OFFSW(rlo + 0, (cA + c * 16) * 2)) = (u16t)p01;
        *(u16t*)((char*)rh + OFFSW(rlo + 1, (cA + c * 16) * 2)) = (u16t)(p01 >> 16);
        *(u16t*)((char*)rh + OFFSW(rlo + 2, (cA + c * 16) * 2)) = (u16t)p23;
        *(u16t*)((char*)rh + OFFSW(rlo + 3, (cA + c * 16) * 2)) = (u16t)(p23 >> 16);
      }
      BAR_LDS();

      float z_[2][4];
      z_[0][0] = sigm2(az0[0]); z_[0][1] = sigm2(az0[1]); z_[0][2] = sigm2(az0[2]); z_[0][3] = sigm2(az0[3]);
      z_[1][0] = sigm2(az1[0]); z_[1][1] = sigm2(az1[1]); z_[1][2] = sigm2(az1[2]); z_[1][3] = sigm2(az1[3]);

      f32x4 ac0, ac1;
      ac0[0] = lo_f(vxh0[0]); ac0[1] = hi_f(vxh0[0]); ac0[2] = lo_f(vxh0[1]); ac0[3] = hi_f(vxh0[1]);
      ac1[0] = lo_f(vxh1[0]); ac1[1] = hi_f(vxh1[0]); ac1[2] = lo_f(vxh1[1]); ac1[3] = hi_f(vxh1[1]);

      {  // reload x regs for t+1
        int tn = t < 1023 ? t + 1 : t;
        size_t oRZ = xoffRZ + (size_t)tn * 32768;
        size_t oH  = xoffH + (size_t)tn * 16384;
        vxr0 = PXR[oRZ]; vxr1 = PXR[oRZ + 64];
        vxz0 = PXZ[oRZ]; vxz1 = PXZ[oRZ + 64];
        vxh0 = PXH[oH];  vxh1 = PXH[oH + 64];
      }

#pragma unroll
      for (int ks = 0; ks < 8; ++ks) {
        s16x8 a_ = LDA_RH(ks);
        ac0 = MF(a_, whh_r[0][ks], ac0);
        ac1 = MF(a_, whh_r[1][ks], ac1);
      }

      float cd[2][4];
      cd[0][0] = tanh2(ac0[0]); cd[0][1] = tanh2(ac0[1]); cd[0][2] = tanh2(ac0[2]); cd[0][3] = tanh2(ac0[3]);
      cd[1][0] = tanh2(ac1[0]); cd[1][1] = tanh2(ac1[1]); cd[1][2] = tanh2(ac1[2]); cd[1][3] = tanh2(ac1[3]);

      // cand: agent-scope relaxed atomic stores (no wbl2 needed)
      size_t ocur = xoffH + (size_t)t * 16384;
      u32x2 s0, s1;
      s0[0] = cvtpk(cd[0][0], cd[0][1]); s0[1] = cvtpk(cd[0][2], cd[0][3]);
      s1[0] = cvtpk(cd[1][0], cd[1][1]); s1[1] = cvtpk(cd[1][2], cd[1][3]);
      st_agent(SXH + ocur, s0);
      st_agent(SXH + ocur + 64, s1);

#pragma unroll
      for (int c = 0; c < 2; ++c) {
#pragma unroll
        for (int j = 0; j < 4; ++j)
          hr_[c][j] = fmaf(z_[c][j], hr_[c][j] - cd[c][j], cd[c][j]);
        u32t p01 = cvtpk(hr_[c][0], hr_[c][1]);
        u32t p23 = cvtpk(hr_[c][2], hr_[c][3]);
        *(u16t*)((char*)hb + OFFSW(rlo + 0, (cA + c * 16) * 2)) = (u16t)p01;
        *(u16t*)((char*)hb + OFFSW(rlo + 1, (cA + c * 16) * 2)) = (u16t)(p01 >> 16);
        *(u16t*)((char*)hb + OFFSW(rlo + 2, (cA + c * 16) * 2)) = (u16t)p23;
        *(u16t*)((char*)hb + OFFSW(rlo + 3, (cA + c * 16) * 2)) = (u16t)(p23 >> 16);
      }

      ZLOAD(bA, 0);
      ZLOAD(bB, 1);
      BAR_LDS();

      // publish completed-step count every 16 steps
      if ((t & 15) == 15) {
        __syncthreads();
        if (tid == 0)
          __hip_atomic_store(prog + wg, t + 1, __ATOMIC_RELAXED,
                             __HIP_MEMORY_SCOPE_AGENT);
      }
    }
#pragma unroll
    for (int c = 0; c < 2; ++c)
#pragma unroll
      for (int j = 0; j < 4; ++j)
        hout[(size_t)(wg * 16 + rlo + j) * 256 + cA + c * 16] = hr_[c][j];

  } else {
    // ======================= consumer =======================
    u16t* cm = smem;
    const int cid = bid - 16;                 // 0..NCONS-1
    const int asw = (lane & 7) << 4;

    // ---- phase A: xproj half-tiles, ascending (i>>3 = t) ----
    // tile i: t = i>>3, q = (i>>1)&3, hh = i&1 (24-combo half).
    for (int i = cid; i < 8192; i += NCONS) {
      const int t = i >> 3, q = (i >> 1) & 3, hh = i & 1;
      const float* xrow = x + ((size_t)t * 256 + q * 64) * 256;
#pragma unroll
      for (int c = 0; c < 8; ++c) {
        int f4 = c * 512 + tid;
        f32v4 v = ((const f32v4*)xrow)[f4];
        u32t lo = f2bf(v[0]) | (f2bf(v[1]) << 16);
        u32t hi = f2bf(v[2]) | (f2bf(v[3]) << 16);
        int row = f4 >> 6, c8 = (f4 & 63) * 8;
        int off = (row * 512 + c8) ^ ((row & 7) << 4);
        u32x2 vv; vv[0] = lo; vv[1] = hi;
        *(u32x2*)((char*)cm + off) = vv;
      }
      __syncthreads();
      const int m2 = w & 1, cg = w >> 1;
      const int arow = m2 * 32 + (lane & 15);
      const int abase = arow * 512 + (lane >> 4) * 16;
      const f32x4 Z = {0.f, 0.f, 0.f, 0.f};
      f32x4 acc[2][6];
#pragma unroll
      for (int s = 0; s < 2; ++s)
#pragma unroll
        for (int p = 0; p < 6; ++p) acc[s][p] = Z;
#pragma unroll
      for (int ks = 0; ks < 8; ++ks) {
        s16x8 a0 = *(const s16x8*)((char*)cm + ((abase + ks * 64) ^ asw));
        s16x8 a1 = *(const s16x8*)((char*)cm + ((abase + 16 * 512 + ks * 64) ^ asw));
#pragma unroll
        for (int p = 0; p < 6; ++p) {
          int pj = hh * 24 + cg * 6 + p;
          int gate = pj >> 4, nb = pj & 15;
          s16x8 b = ((const s16x8*)wpack + gate * 8192)[(nb * 8 + ks) * 64 + lane];
          acc[0][p] = MF(a0, b, acc[0][p]);
          acc[1][p] = MF(a1, b, acc[1][p]);
        }
      }
#pragma unroll
      for (int p = 0; p < 6; ++p) {
        int pj = hh * 24 + cg * 6 + p;
        int gate = pj >> 4, nb = pj & 15;
        const float* bp = gate == 0 ? br : gate == 1 ? bz : bh;
        float bs = (gate == 2) ? 2.0f * L2E : L2E;
        float bv = bp[nb * 16 + (lane & 15)] * bs;
        u16t* op = gate == 0 ? xr_p : gate == 1 ? xz_p : xh_p;
#pragma unroll
        for (int s = 0; s < 2; ++s) {
          int wg2 = q * 4 + m2 * 2 + s;
          u32t lo = f2bf(acc[s][p][0] + bv) | (f2bf(acc[s][p][1] + bv) << 16);
          u32t hi = f2bf(acc[s][p][2] + bv) | (f2bf(acc[s][p][3] + bv) << 16);
          size_t off = (gate == 2)
              ? (size_t)t * 16384 + wg2 * 1024 + nb * 64 + lane
              : (size_t)t * 32768 + wg2 * 1024 + nb * 64 + lane;
          u32x2 vv; vv[0] = lo; vv[1] = hi;
          st_agent((u32x2*)op + off, vv);
        }
      }
      __syncthreads();   // drains all waves' vmcnt (sc-stores retired)
      if (tid == 0)
        __hip_atomic_store(xprog + cid, i + NCONS, __ATOMIC_RELAXED,
                           __HIP_MEMORY_SCOPE_AGENT);
    }

    // ---- phase B: out-tiles, gated on scan progress ----
    const s16x8* wo = (const s16x8*)wpack + 6 * 8192;
    const int mt = w & 3, nbs = (w >> 2) * 8;
    const int arow = mt * 16 + (lane & 15);
    const int abase = arow * 512 + (lane >> 4) * 16;
    const f32x4 Z = {0.f, 0.f, 0.f, 0.f};
    int lastmn = 0;

    for (int tile = cid; tile < 4096; tile += NCONS) {
      const int t = tile >> 2, q = tile & 3;
      const int need = t + 1;
      if (lastmn < need) {
        if (tid == 0) {
          int mn;
          for (;;) {
            mn = 1 << 30;
#pragma unroll
            for (int s = 0; s < 16; ++s)
              mn = min(mn, __hip_atomic_load(prog + s, __ATOMIC_RELAXED,
                                             __HIP_MEMORY_SCOPE_AGENT));
            if (mn >= need) break;
            __builtin_amdgcn_s_sleep(8);
            __builtin_amdgcn_s_sleep(8);
            __builtin_amdgcn_s_sleep(8);
            __builtin_amdgcn_s_sleep(8);
          }
          bc[0] = mn;
        }
        __syncthreads();
        lastmn = bc[0];
        __syncthreads();
      }
      // stage cand quarter via agent-scope atomic loads (dodge stale L2)
      const u32x2* src = (const u32x2*)xh_p + ((size_t)t * 16 + q * 4) * 1024;
#pragma unroll
      for (int it = 0; it < 8; ++it) {
        int i = it * 512 + tid;
        u32x2 v = ld_agent(src + i);
        int wg_l = i >> 10, nb = (i >> 6) & 15, ls = i & 63;
        int brow = wg_l * 16 + (ls >> 4) * 4;
        int hc2 = (nb * 16 + (ls & 15)) * 2;
        u16t ev[4] = {(u16t)(v[0] & 0xffff), (u16t)(v[0] >> 16),
                      (u16t)(v[1] & 0xffff), (u16t)(v[1] >> 16)};
#pragma unroll
        for (int j = 0; j < 4; ++j)
          *(u16t*)((char*)cm + OFFSW(brow + j, hc2)) = ev[j];
      }
      __syncthreads();
      f32x4 acc[8] = {Z, Z, Z, Z, Z, Z, Z, Z};
#pragma unroll
      for (int ks = 0; ks < 8; ++ks) {
        s16x8 a = *(const s16x8*)((char*)cm + ((abase + ks * 64) ^ asw));
#pragma unroll
        for (int p = 0; p < 8; ++p)
          acc[p] = MF(a, wo[((nbs + p) * 8 + ks) * 64 + lane], acc[p]);
      }
#pragma unroll
      for (int p = 0; p < 8; ++p) {
        int col = (nbs + p) * 16 + (lane & 15);
        float bv = bout[col];
        size_t rb = (size_t)t * 256 + q * 64 + mt * 16 + (lane >> 4) * 4;
#pragma unroll
        for (int j = 0; j < 4; ++j)
          __builtin_nontemporal_store(acc[p][j] + bv, &out[(rb + j) * 256 + col]);
      }
      __syncthreads();
    }
  }
}

extern "C" void kernel_launch(void* const* d_in, const int* in_sizes, int n_in,
                              void* d_out, int out_size, void* d_ws, size_t ws_size,
                              hipStream_t stream) {
  const float* x    = (const float*)d_in[0];
  const float* h0   = (const float*)d_in[1];
  const float* wxr  = (const float*)d_in[2];
  const float* whr  = (const float*)d_in[3];
  const float* br   = (const float*)d_in[4];
  const float* wxz  = (const float*)d_in[5];
  const float* whz  = (const float*)d_in[6];
  const float* bz   = (const float*)d_in[7];
  const float* wxh  = (const float*)d_in[8];
  const float* whh  = (const float*)d_in[9];
  const float* bh   = (const float*)d_in[10];
  const float* wout = (const float*)d_in[11];
  const float* bout = (const float*)d_in[12];

  float* out  = (float*)d_out;
  u16t* wpack = (u16t*)d_ws;                               // 896 KB
  int*  prog  = (int*)((char*)d_ws + 917504);              // 512 B (prog+xprog)
  u16t* xh_p  = (u16t*)((char*)d_ws + (1u << 20));         // 128 MB (cand in-place)
  u16t* xr_p  = (u16t*)d_out;                              // interleaved block base
  u16t* xz_p  = (u16t*)d_out + 65536;                      // +128 KB within block
  float* hout = (float*)((char*)d_out + 268435456ull);     // h_final slot

  pack_w<<<1792, 256, 0, stream>>>(wxr, wxz, wxh, whr, whz, whh, wout, wpack, prog);
  gru_fused<<<16 + NCONS, 512, 0, stream>>>(x, h0, wpack, br, bz, bh,
                                            xr_p, xz_p, xh_p, hout, prog,
                                            bout, out);
}